// Round 11
// baseline (963.220 us; speedup 1.0000x reference)
//
#include <hip/hip_runtime.h>
#include <math.h>

#define NN 10000
#define NE 160000
#define FDIM 128
#define NRBF 20
#define PI_F 3.14159265358979323846f
#define LDP 40  // LDS row pitch in bf16 elems (80 B -> 16B-aligned b128 rows)

typedef short bf16x8 __attribute__((ext_vector_type(8)));
typedef float f32x4 __attribute__((ext_vector_type(4)));
typedef float v2f __attribute__((ext_vector_type(2)));

__device__ __forceinline__ unsigned short f2bf_rne(float v) {
    unsigned int u = __float_as_uint(v);
    u += 0x7FFF + ((u >> 16) & 1);
    return (unsigned short)(u >> 16);
}
__device__ __forceinline__ float bf2f(unsigned short b) {
    return __uint_as_float(((unsigned int)b) << 16);
}

// ---------------------------------------------------------------------------
// Pass 1: src histogram
// ---------------------------------------------------------------------------
__global__ void edge_count_kernel(const int* __restrict__ nbr, int* __restrict__ counts)
{
    int e = blockIdx.x * blockDim.x + threadIdx.x;
    if (e >= NE) return;
    atomicAdd(&counts[nbr[2 * e]], 1);
}

// ---------------------------------------------------------------------------
// Single-block exclusive scan over counts -> offsets (N+1)
// ---------------------------------------------------------------------------
__global__ void scan_kernel(const int* __restrict__ counts, int* __restrict__ offsets)
{
    __shared__ int sd[1024];
    __shared__ int carry;
    if (threadIdx.x == 0) carry = 0;
    __syncthreads();
    for (int base = 0; base < NN; base += 1024) {
        int i = base + threadIdx.x;
        int v = (i < NN) ? counts[i] : 0;
        sd[threadIdx.x] = v;
        __syncthreads();
        for (int off = 1; off < 1024; off <<= 1) {
            int t = (threadIdx.x >= off) ? sd[threadIdx.x - off] : 0;
            __syncthreads();
            sd[threadIdx.x] += t;
            __syncthreads();
        }
        if (i < NN) offsets[i] = carry + sd[threadIdx.x] - v;
        __syncthreads();
        if (threadIdx.x == 0) carry += sd[1023];
        __syncthreads();
    }
    if (threadIdx.x == 0) offsets[NN] = carry;
}

// ---------------------------------------------------------------------------
// Pass 2: geometry into CSR-permuted slots (fp32).
// ---------------------------------------------------------------------------
__global__ void edge_geom_fill_kernel(const float* __restrict__ xyz, const int* __restrict__ nbr,
                                      const int* __restrict__ offsets, int* __restrict__ cnt2,
                                      int* __restrict__ dstP, float4* __restrict__ ueP,
                                      float* __restrict__ rbfP)
{
    int e = blockIdx.x * blockDim.x + threadIdx.x;
    if (e >= NE) return;
    int s = nbr[2 * e], d = nbr[2 * e + 1];
    float dx = xyz[3 * d + 0] - xyz[3 * s + 0];
    float dy = xyz[3 * d + 1] - xyz[3 * s + 1];
    float dz = xyz[3 * d + 2] - xyz[3 * s + 2];
    float dist = sqrtf(dx * dx + dy * dy + dz * dz);
    float inv = 1.0f / dist;
    int p = offsets[s] + atomicAdd(&cnt2[s], 1);
    dstP[p] = d;
    const float c = PI_F / 5.0f;
    float env = (dist < 5.0f) ? 0.5f * (cosf(c * dist) + 1.0f) : 0.0f;
    ueP[p] = make_float4(dx * inv, dy * inv, dz * inv, env);
#pragma unroll
    for (int k = 0; k < NRBF; k++)
        rbfP[NRBF * p + k] = sinf((float)(k + 1) * c * dist) * inv;
}

// ---------------------------------------------------------------------------
// Transpose + split: src [3][K][N] fp32 -> th/tl [3][N][K] bf16 pair.
// ---------------------------------------------------------------------------
__global__ void tsplit_kernel(const float* __restrict__ src,
                              unsigned short* __restrict__ th,
                              unsigned short* __restrict__ tl, int K, int N)
{
    int idx = blockIdx.x * blockDim.x + threadIdx.x;
    int tot = 3 * K * N;
    if (idx >= tot) return;
    int l = idx / (K * N);
    int rem = idx - l * (K * N);
    int k = rem / N, n = rem - k * N;
    float v = src[idx];
    unsigned short hh = f2bf_rne(v);
    size_t o = (size_t)l * K * N + (size_t)n * K + k;
    th[o] = hh;
    tl[o] = f2bf_rne(v - bf2f(hh));
}

// ---------------------------------------------------------------------------
// Build transposed+split [U|V]: out [3][256][128] (n-major, k inner).
// ---------------------------------------------------------------------------
__global__ void build_uvcat_t_kernel(const float* __restrict__ updU,
                                     const float* __restrict__ updV,
                                     unsigned short* __restrict__ th,
                                     unsigned short* __restrict__ tl)
{
    int idx = blockIdx.x * blockDim.x + threadIdx.x;
    if (idx >= 3 * 128 * 256) return;
    int ly = idx / (128 * 256);
    int rem = idx % (128 * 256);
    int k = rem >> 8, j = rem & 255;
    float v = (j < 128) ? updU[(ly * 128 + k) * 128 + j]
                        : updV[(ly * 128 + k) * 128 + (j - 128)];
    unsigned short hh = f2bf_rne(v);
    size_t o = (size_t)ly * 128 * 256 + (size_t)j * 128 + k;
    th[o] = hh;
    tl[o] = f2bf_rne(v - bf2f(hh));
}

// ---------------------------------------------------------------------------
// Split-bf16 MFMA GEMM v6: B fragments loaded DIRECTLY from global (weights
// are [N][K] pre-transposed + pre-split, L2-resident) — no B LDS staging.
// Only A goes through LDS. Per K-step per wave: 2 LDS writes + 4 LDS frag
// reads (was 12 b128 LDS ops in v5). Math bit-identical to v5.
// ASPLIT: A pre-split row-major [M][K]. else fp32 A (CAT: two 128 halves).
// OSPLIT: epilogue writes split bf16 (Ch/Cl row-major [M][N]).
// ---------------------------------------------------------------------------
template <int ACT, int CAT, int ASPLIT, int OSPLIT>
__global__ __launch_bounds__(256) void gemm6_kernel(
    const float* __restrict__ Af, const float* __restrict__ A1,
    const unsigned short* __restrict__ Agh, const unsigned short* __restrict__ Agl,
    const unsigned short* __restrict__ Wth, const unsigned short* __restrict__ Wtl,
    const float* __restrict__ bias,
    float* __restrict__ C, unsigned short* __restrict__ Ch, unsigned short* __restrict__ Cl,
    int M, int K, int N)
{
    __shared__ __align__(16) unsigned short Ah[64 * LDP];
    __shared__ __align__(16) unsigned short Al[64 * LDP];

    int tid = threadIdx.x;
    int row0 = blockIdx.y * 64, col0 = blockIdx.x * 64;
    int lane = tid & 63, wave = tid >> 6;
    int mb = (wave & 1) * 32, nb = (wave >> 1) * 32;
    int lm = lane & 15, quad = lane >> 4;

    f32x4 acc[2][2] = {};

    int sm = tid >> 2;           // 0..63: A row
    int sk = (tid & 3) * 8;      // 0,8,16,24: k offset (8 elems)

    // B row bases (invariant): wave reads rows col0+nb+nt*16+lm
    const unsigned short* Bh0 = Wth + (size_t)(col0 + nb + lm) * K;
    const unsigned short* Bl0 = Wtl + (size_t)(col0 + nb + lm) * K;
    const unsigned short* Bh1 = Wth + (size_t)(col0 + nb + 16 + lm) * K;
    const unsigned short* Bl1 = Wtl + (size_t)(col0 + nb + 16 + lm) * K;

    for (int k0 = 0; k0 < K; k0 += 32) {
        // ---- stage A: 64 rows x 32 k into LDS ----
        {
            int ar = row0 + sm;
            if (ASPLIT) {
                uint4 h = {0, 0, 0, 0}, l = {0, 0, 0, 0};
                if (ar < M) {
                    h = *(const uint4*)(Agh + (size_t)ar * K + k0 + sk);
                    l = *(const uint4*)(Agl + (size_t)ar * K + k0 + sk);
                }
                *(uint4*)&Ah[sm * LDP + sk] = h;
                *(uint4*)&Al[sm * LDP + sk] = l;
            } else {
                float4 a0 = make_float4(0.f, 0.f, 0.f, 0.f);
                float4 a1 = make_float4(0.f, 0.f, 0.f, 0.f);
                if (ar < M) {
                    int kk = k0 + sk;
                    const float* Ab;
                    if (CAT) Ab = (kk < 128) ? Af + (size_t)ar * 128 + kk
                                             : A1 + (size_t)ar * 128 + (kk - 128);
                    else     Ab = Af + (size_t)ar * K + kk;
                    a0 = *(const float4*)Ab;
                    a1 = *(const float4*)(Ab + 4);
                }
                float v[8] = {a0.x, a0.y, a0.z, a0.w, a1.x, a1.y, a1.z, a1.w};
                unsigned short hs[8], ls[8];
#pragma unroll
                for (int i = 0; i < 8; i++) {
                    unsigned short h = f2bf_rne(v[i]);
                    hs[i] = h; ls[i] = f2bf_rne(v[i] - bf2f(h));
                }
                *(uint4*)&Ah[sm * LDP + sk] = *(uint4*)hs;
                *(uint4*)&Al[sm * LDP + sk] = *(uint4*)ls;
            }
        }
        // ---- B fragments direct from global (L2-resident weights) ----
        bf16x8 fbh[2], fbl[2];
        fbh[0] = *(const bf16x8*)(Bh0 + k0 + quad * 8);
        fbl[0] = *(const bf16x8*)(Bl0 + k0 + quad * 8);
        fbh[1] = *(const bf16x8*)(Bh1 + k0 + quad * 8);
        fbl[1] = *(const bf16x8*)(Bl1 + k0 + quad * 8);
        __syncthreads();
        bf16x8 fah[2], fal[2];
#pragma unroll
        for (int mt = 0; mt < 2; mt++) {
            int r = mb + mt * 16 + lm;
            fah[mt] = *(const bf16x8*)&Ah[r * LDP + quad * 8];
            fal[mt] = *(const bf16x8*)&Al[r * LDP + quad * 8];
        }
#pragma unroll
        for (int mt = 0; mt < 2; mt++)
#pragma unroll
            for (int nt = 0; nt < 2; nt++) {
                acc[mt][nt] = __builtin_amdgcn_mfma_f32_16x16x32_bf16(
                    fah[mt], fbh[nt], acc[mt][nt], 0, 0, 0);
                acc[mt][nt] = __builtin_amdgcn_mfma_f32_16x16x32_bf16(
                    fah[mt], fbl[nt], acc[mt][nt], 0, 0, 0);
                acc[mt][nt] = __builtin_amdgcn_mfma_f32_16x16x32_bf16(
                    fal[mt], fbh[nt], acc[mt][nt], 0, 0, 0);
            }
        __syncthreads();
    }
#pragma unroll
    for (int mt = 0; mt < 2; mt++)
#pragma unroll
        for (int nt = 0; nt < 2; nt++) {
            int c = col0 + nb + nt * 16 + lm;
            float bv = bias ? bias[c] : 0.f;
#pragma unroll
            for (int reg = 0; reg < 4; reg++) {
                int r = row0 + mb + mt * 16 + quad * 4 + reg;
                if (r >= M) continue;
                float v = acc[mt][nt][reg] + bv;
                if (ACT) v = v / (1.0f + expf(-v));
                if (OSPLIT) {
                    unsigned short h = f2bf_rne(v);
                    Ch[(size_t)r * N + c] = h;
                    Cl[(size_t)r * N + c] = f2bf_rne(v - bf2f(h));
                } else {
                    C[(size_t)r * N + c] = v;
                }
            }
        }
}

// ---------------------------------------------------------------------------
// Gather (R9, PROTECTED — byte-identical): plane-split halves, packed w-dot,
// distW pinned via opaque asm. L0=1 skips zero V/Vbar.
// ---------------------------------------------------------------------------
template <int L0>
__global__ __launch_bounds__(256, 4) void gather_kernel(
    const int* __restrict__ offsets, const int* __restrict__ dstP,
    const float4* __restrict__ ueP, const float* __restrict__ rbfP,
    const float* __restrict__ phi,
    const float* __restrict__ distW, const float* __restrict__ distb,
    const float* __restrict__ Vold, const float* __restrict__ Vbold,
    float* __restrict__ H, float* __restrict__ Sbar,
    float* __restrict__ Vnew, float* __restrict__ Vbnew)
{
    int n = blockIdx.x;
    int t = threadIdx.x;
    int half = t >> 7;          // wave-uniform
    int f = t & 127;
    int po = half * 256;

    v2f wv2[30];
#pragma unroll
    for (int q = 0; q < 10; q++)
#pragma unroll
        for (int c = 0; c < 3; c++) {
            wv2[q * 3 + c].x = distW[(2 * q) * 640 + po + c * 128 + f];
            wv2[q * 3 + c].y = distW[(2 * q + 1) * 640 + po + c * 128 + f];
        }
#pragma unroll
    for (int i = 0; i < 30; i++) asm volatile("" : "+v"(wv2[i]));

    float bA = distb[po + f], bB = distb[po + 128 + f], bC = distb[po + 256 + f];

    const float* Vsel = half ? Vbold : Vold;

    float sacc = 0.f, acc0 = 0.f, acc1 = 0.f, acc2 = 0.f;
    int e0 = offsets[n], e1 = offsets[n + 1];
    for (int p = e0; p < e1; ++p) {
        int d = dstP[p];
        float4 ue = ueP[p];
        float r[NRBF];
#pragma unroll
        for (int q = 0; q < NRBF / 4; q++) {
            float4 rv = *(const float4*)&rbfP[NRBF * p + 4 * q];
            r[4 * q + 0] = rv.x; r[4 * q + 1] = rv.y;
            r[4 * q + 2] = rv.z; r[4 * q + 3] = rv.w;
        }
        v2f aA = {0.f, 0.f}, aB = {0.f, 0.f}, aC = {0.f, 0.f};
#pragma unroll
        for (int q = 0; q < 10; q++) {
            v2f r2; r2.x = r[2 * q]; r2.y = r[2 * q + 1];
            aA += r2 * wv2[q * 3 + 0];
            aB += r2 * wv2[q * 3 + 1];
            aC += r2 * wv2[q * 3 + 2];
        }
        float ev = ue.w;
        float wA = (aA.x + aA.y + bA) * ev;
        float wB = (aB.x + aB.y + bB) * ev;
        float wC = (aC.x + aC.y + bC) * ev;
        const float* ph = phi + (size_t)d * 640 + po;
        float iA = ph[f] * wA;
        float iB = ph[128 + f] * wB;
        float iC = ph[256 + f] * wC;
        float dir = half ? iA : iC;
        sacc += iB;
        if (L0) {
            acc0 += dir * ue.x;
            acc1 += dir * ue.y;
            acc2 += dir * ue.z;
        } else {
            float gate = half ? iC : iA;
            const float* vd = Vsel + (size_t)d * 384;
            acc0 += dir * ue.x + gate * vd[f];
            acc1 += dir * ue.y + gate * vd[128 + f];
            acc2 += dir * ue.z + gate * vd[256 + f];
        }
    }
    if (half == 0) H[n * 128 + f] += sacc;
    else           Sbar[n * 128 + f] += sacc;
    float* vn = (half ? Vbnew : Vnew) + (size_t)n * 384;
    if (L0) {
        vn[f] = acc0; vn[128 + f] = acc1; vn[256 + f] = acc2;
    } else {
        const float* vo = Vsel + (size_t)n * 384;
        vn[f]       = vo[f]       + acc0;
        vn[128 + f] = vo[128 + f] + acc1;
        vn[256 + f] = vo[256 + f] + acc2;
    }
}

// ---------------------------------------------------------------------------
// norm/dot from fused uv2 [3N x 256].
// ---------------------------------------------------------------------------
__global__ void norm_kernel(const float* __restrict__ uv2,
                            float* __restrict__ vnorm, float* __restrict__ dotb)
{
    int idx = blockIdx.x * blockDim.x + threadIdx.x;
    if (idx >= NN * 128) return;
    int n = idx >> 7, g = idx & 127;
    const float* base = uv2 + (size_t)n * 768;
    float u0 = base[g],       u1 = base[256 + g], u2 = base[512 + g];
    float v0 = base[128 + g], v1 = base[384 + g], v2 = base[640 + g];
    dotb[idx] = u0 * v0 + u1 * v1 + u2 * v2;
    vnorm[idx] = sqrtf(v0 * v0 + v1 * v1 + v2 * v2 + 1e-15f);
}

// ---------------------------------------------------------------------------
// Final per-layer update: H += a1*dot + a2 ; V += a0*u_v (u from uv2).
// ---------------------------------------------------------------------------
template <int LAST>
__global__ void final_update_kernel(const float* __restrict__ a,
                                    const float* __restrict__ dotb,
                                    const float* __restrict__ uv2,
                                    float* __restrict__ H,
                                    float* __restrict__ Vplanar,
                                    float* __restrict__ Vout)
{
    int idx = blockIdx.x * blockDim.x + threadIdx.x;
    if (idx >= NN * 128) return;
    int n = idx >> 7, g = idx & 127;
    float a0 = a[n * 384 + g];
    float a1 = a[n * 384 + 128 + g];
    float a2 = a[n * 384 + 256 + g];
    H[idx] += a1 * dotb[idx] + a2;
    float* vp = Vplanar + (size_t)n * 384;
    const float* ub = uv2 + (size_t)n * 768;
    float v0 = vp[g]       + a0 * ub[g];
    float v1 = vp[128 + g] + a0 * ub[256 + g];
    float v2 = vp[256 + g] + a0 * ub[512 + g];
    if (LAST) {
        float* o = Vout + (size_t)n * 384 + g * 3;
        o[0] = v0; o[1] = v1; o[2] = v2;
    } else {
        vp[g] = v0; vp[128 + g] = v1; vp[256 + g] = v2;
    }
}

// ---------------------------------------------------------------------------
extern "C" void kernel_launch(void* const* d_in, const int* in_sizes, int n_in,
                              void* d_out, int out_size, void* d_ws, size_t ws_size,
                              hipStream_t stream)
{
    const float* xyz    = (const float*)d_in[0];
    const int*   nbr    = (const int*)d_in[1];
    const float* H_in   = (const float*)d_in[3];
    const float* msgW1  = (const float*)d_in[4];
    const float* msgb1  = (const float*)d_in[5];
    const float* msgW2  = (const float*)d_in[6];
    const float* msgb2  = (const float*)d_in[7];
    const float* distW  = (const float*)d_in[8];
    const float* distb  = (const float*)d_in[9];
    const float* updU   = (const float*)d_in[10];
    const float* updV   = (const float*)d_in[11];
    const float* updW1  = (const float*)d_in[12];
    const float* updb1  = (const float*)d_in[13];
    const float* updW2  = (const float*)d_in[14];
    const float* updb2  = (const float*)d_in[15];

    float* out  = (float*)d_out;
    float* H    = out;                 // N*128
    float* Vout = out + NN * 128;      // N*384 interleaved (n,f,3)

    // ---- workspace carve ----
    float* f = (float*)d_ws;
    float* Va   = f; f += NN * 384;    // planar V buffers
    float* Vb   = f; f += NN * 384;
    float* Vba  = f; f += NN * 384;
    float* Vbb  = f; f += NN * 384;
    float* Sbar = f; f += NN * 128;
    float* phi  = f; f += NN * 640;
    float* uv2  = f; f += NN * 768;    // [3N x 256] fused u_v|v_v
    float4* ueP = (float4*)f; f += NE * 4;
    float* rbfP  = f; f += NE * NRBF;
    unsigned short* us = (unsigned short*)f;
    unsigned short* X1h = us; us += NN * 256;
    unsigned short* X1l = us; us += NN * 256;
    unsigned short* W1h = us; us += 3 * 256 * 256;   // transposed [N=256][K=256]
    unsigned short* W1l = us; us += 3 * 256 * 256;
    unsigned short* W2h = us; us += 3 * 256 * 640;   // transposed [N=640][K=256]
    unsigned short* W2l = us; us += 3 * 256 * 640;
    unsigned short* UVh = us; us += 3 * 128 * 256;   // transposed [N=256][K=128]
    unsigned short* UVl = us; us += 3 * 128 * 256;
    unsigned short* uW1h = us; us += 3 * 256 * 128;  // transposed [N=128][K=256]
    unsigned short* uW1l = us; us += 3 * 256 * 128;
    unsigned short* uW2h = us; us += 3 * 128 * 384;  // transposed [N=384][K=128]
    unsigned short* uW2l = us; us += 3 * 128 * 384;
    int* ip = (int*)(((size_t)us + 15) & ~(size_t)15);
    int* counts  = ip; ip += NN;
    int* offsets = ip; ip += NN + 1;
    int* cnt2    = ip; ip += NN;
    int* dstP    = ip; ip += NE;
    // aliases into dead phi region (phi dead after gather each layer)
    float* vnorm = phi;
    float* dotb  = phi + NN * 128;
    float* abuf  = phi + NN * 256;     // N*384

    // ---- init ----
    hipMemsetAsync(counts, 0, NN * sizeof(int), stream);
    hipMemsetAsync(cnt2, 0, NN * sizeof(int), stream);
    hipMemsetAsync(Sbar, 0, (size_t)NN * 128 * sizeof(float), stream);
    hipMemcpyAsync(H, H_in, (size_t)NN * 128 * sizeof(float),
                   hipMemcpyDeviceToDevice, stream);

    // ---- edge CSR + geometry + weight transpose/split ----
    edge_count_kernel<<<(NE + 255) / 256, 256, 0, stream>>>(nbr, counts);
    scan_kernel<<<1, 1024, 0, stream>>>(counts, offsets);
    edge_geom_fill_kernel<<<(NE + 255) / 256, 256, 0, stream>>>(xyz, nbr, offsets, cnt2,
                                                                dstP, ueP, rbfP);
    tsplit_kernel<<<(3 * 256 * 256 + 255) / 256, 256, 0, stream>>>(msgW1, W1h, W1l, 256, 256);
    tsplit_kernel<<<(3 * 256 * 640 + 255) / 256, 256, 0, stream>>>(msgW2, W2h, W2l, 256, 640);
    tsplit_kernel<<<(3 * 256 * 128 + 255) / 256, 256, 0, stream>>>(updW1, uW1h, uW1l, 256, 128);
    tsplit_kernel<<<(3 * 128 * 384 + 255) / 256, 256, 0, stream>>>(updW2, uW2h, uW2l, 128, 384);
    build_uvcat_t_kernel<<<(3 * 128 * 256 + 255) / 256, 256, 0, stream>>>(updU, updV, UVh, UVl);

    for (int l = 0; l < 3; ++l) {
        const float* b1 = msgb1 + (size_t)l * 256;
        const float* b2 = msgb2 + (size_t)l * 640;
        const float* dW = distW + (size_t)l * NRBF * 640;
        const float* db = distb + (size_t)l * 640;
        const float* ub1 = updb1 + (size_t)l * 128;
        const float* ub2 = updb2 + (size_t)l * 384;
        const unsigned short *w1h = W1h + (size_t)l * 256 * 256, *w1l = W1l + (size_t)l * 256 * 256;
        const unsigned short *w2h = W2h + (size_t)l * 256 * 640, *w2l = W2l + (size_t)l * 256 * 640;
        const unsigned short *uvh = UVh + (size_t)l * 128 * 256, *uvl = UVl + (size_t)l * 128 * 256;
        const unsigned short *u1h = uW1h + (size_t)l * 256 * 128, *u1l = uW1l + (size_t)l * 256 * 128;
        const unsigned short *u2h = uW2h + (size_t)l * 128 * 384, *u2l = uW2l + (size_t)l * 128 * 384;

        float *Vold, *Vnew, *Vbold, *Vbnew;
        if (l == 0)      { Vold = Va; Vnew = Vb; Vbold = Vba; Vbnew = Vbb; }
        else if (l == 1) { Vold = Vb; Vnew = Va; Vbold = Vbb; Vbnew = Vba; }
        else             { Vold = Va; Vnew = Vb; Vbold = Vba; Vbnew = Vbb; }

        // X1 = silu([H|Sbar] @ W1 + b1)  (split-bf16 output)
        {
            dim3 g(256 / 64, (NN + 63) / 64);
            gemm6_kernel<1, 1, 0, 1><<<g, 256, 0, stream>>>(
                H, Sbar, nullptr, nullptr, w1h, w1l, b1,
                nullptr, X1h, X1l, NN, 256, 256);
        }
        // phi = X1 @ W2 + b2  (fp32 output)
        {
            dim3 g(640 / 64, (NN + 63) / 64);
            gemm6_kernel<0, 0, 1, 0><<<g, 256, 0, stream>>>(
                nullptr, nullptr, X1h, X1l, w2h, w2l, b2,
                phi, nullptr, nullptr, NN, 256, 640);
        }

        // message gather
        if (l == 0)
            gather_kernel<1><<<NN, 256, 0, stream>>>(offsets, dstP, ueP, rbfP,
                                                     phi, dW, db, Vold, Vbold,
                                                     H, Sbar, Vnew, Vbnew);
        else
            gather_kernel<0><<<NN, 256, 0, stream>>>(offsets, dstP, ueP, rbfP,
                                                     phi, dW, db, Vold, Vbold,
                                                     H, Sbar, Vnew, Vbnew);

        // uv2[3N x 256] = Vplanar[3N x 128] @ [U|V]
        {
            dim3 g(256 / 64, (3 * NN + 63) / 64);
            gemm6_kernel<0, 0, 0, 0><<<g, 256, 0, stream>>>(
                Vnew, nullptr, nullptr, nullptr, uvh, uvl, nullptr,
                uv2, nullptr, nullptr, 3 * NN, 128, 256);
        }
        norm_kernel<<<(NN * 128 + 255) / 256, 256, 0, stream>>>(uv2, vnorm, dotb);

        // X1 = silu([H|vnorm] @ uW1 + ub1)  (split output, 128 wide)
        {
            dim3 g(128 / 64, (NN + 63) / 64);
            gemm6_kernel<1, 1, 0, 1><<<g, 256, 0, stream>>>(
                H, vnorm, nullptr, nullptr, u1h, u1l, ub1,
                nullptr, X1h, X1l, NN, 256, 128);
        }
        // abuf = X1 @ uW2 + ub2
        {
            dim3 g(384 / 64, (NN + 63) / 64);
            gemm6_kernel<0, 0, 1, 0><<<g, 256, 0, stream>>>(
                nullptr, nullptr, X1h, X1l, u2h, u2l, ub2,
                abuf, nullptr, nullptr, NN, 128, 384);
        }

        // H += a1*dot + a2 ; V += a0*u_v
        if (l < 2)
            final_update_kernel<0><<<(NN * 128 + 255) / 256, 256, 0, stream>>>(
                abuf, dotb, uv2, H, Vnew, nullptr);
        else
            final_update_kernel<1><<<(NN * 128 + 255) / 256, 256, 0, stream>>>(
                abuf, dotb, uv2, H, Vnew, Vout);
    }
}

// Round 12
// 849.777 us; speedup vs baseline: 1.1335x; 1.1335x over previous
//
#include <hip/hip_runtime.h>
#include <math.h>

#define NN 10000
#define NE 160000
#define FDIM 128
#define NRBF 20
#define PI_F 3.14159265358979323846f
#define LDP 40  // LDS row pitch in bf16 elems (80 B -> 16B-aligned b128 rows)

typedef short bf16x8 __attribute__((ext_vector_type(8)));
typedef float f32x4 __attribute__((ext_vector_type(4)));
typedef float v2f __attribute__((ext_vector_type(2)));

__device__ __forceinline__ unsigned short f2bf_rne(float v) {
    unsigned int u = __float_as_uint(v);
    u += 0x7FFF + ((u >> 16) & 1);
    return (unsigned short)(u >> 16);
}
__device__ __forceinline__ float bf2f(unsigned short b) {
    return __uint_as_float(((unsigned int)b) << 16);
}

// ---------------------------------------------------------------------------
// Pass 1: src histogram
// ---------------------------------------------------------------------------
__global__ void edge_count_kernel(const int* __restrict__ nbr, int* __restrict__ counts)
{
    int e = blockIdx.x * blockDim.x + threadIdx.x;
    if (e >= NE) return;
    atomicAdd(&counts[nbr[2 * e]], 1);
}

// ---------------------------------------------------------------------------
// Fast single-block scan: 10 nodes/thread serial + one 1024-wide LDS scan.
// ---------------------------------------------------------------------------
__global__ void scan_kernel(const int* __restrict__ counts, int* __restrict__ offsets)
{
    __shared__ int sd[1024];
    int tid = threadIdx.x;
    int base = tid * 10;
    int loc[10];
    int s = 0;
#pragma unroll
    for (int j = 0; j < 10; j++) {
        int i = base + j;
        loc[j] = s;
        int v = (i < NN) ? counts[i] : 0;
        s += v;
    }
    sd[tid] = s;
    __syncthreads();
    for (int off = 1; off < 1024; off <<= 1) {
        int t = (tid >= off) ? sd[tid - off] : 0;
        __syncthreads();
        sd[tid] += t;
        __syncthreads();
    }
    int carry = sd[tid] - s;   // exclusive prefix of this thread's chunk
#pragma unroll
    for (int j = 0; j < 10; j++) {
        int i = base + j;
        if (i < NN) offsets[i] = carry + loc[j];
    }
    if (tid == 1023) offsets[NN] = sd[1023];
}

// ---------------------------------------------------------------------------
// Pass 2: geometry into CSR-permuted slots (fp32).
// ---------------------------------------------------------------------------
__global__ void edge_geom_fill_kernel(const float* __restrict__ xyz, const int* __restrict__ nbr,
                                      const int* __restrict__ offsets, int* __restrict__ cnt2,
                                      int* __restrict__ dstP, float4* __restrict__ ueP,
                                      float* __restrict__ rbfP)
{
    int e = blockIdx.x * blockDim.x + threadIdx.x;
    if (e >= NE) return;
    int s = nbr[2 * e], d = nbr[2 * e + 1];
    float dx = xyz[3 * d + 0] - xyz[3 * s + 0];
    float dy = xyz[3 * d + 1] - xyz[3 * s + 1];
    float dz = xyz[3 * d + 2] - xyz[3 * s + 2];
    float dist = sqrtf(dx * dx + dy * dy + dz * dz);
    float inv = 1.0f / dist;
    int p = offsets[s] + atomicAdd(&cnt2[s], 1);
    dstP[p] = d;
    const float c = PI_F / 5.0f;
    float env = (dist < 5.0f) ? 0.5f * (cosf(c * dist) + 1.0f) : 0.0f;
    ueP[p] = make_float4(dx * inv, dy * inv, dz * inv, env);
#pragma unroll
    for (int k = 0; k < NRBF; k++)
        rbfP[NRBF * p + k] = sinf((float)(k + 1) * c * dist) * inv;
}

// ---------------------------------------------------------------------------
// Merged weight prep: all 4 transposed splits + [U|V] concat in one kernel.
// Segment s: 0=W1(K256,N256) 1=W2(K256,N640) 2=uW1(K256,N128) 3=uW2(K128,N384)
// 4=UVcat(K128,N256 from updU|updV).
// ---------------------------------------------------------------------------
#define S0 (3*256*256)
#define S1 (3*256*640)
#define S2 (3*256*128)
#define S3 (3*128*384)
#define S4 (3*128*256)
__global__ void weight_prep_kernel(const float* __restrict__ msgW1,
                                   const float* __restrict__ msgW2,
                                   const float* __restrict__ updW1,
                                   const float* __restrict__ updW2,
                                   const float* __restrict__ updU,
                                   const float* __restrict__ updV,
                                   unsigned short* __restrict__ W1h, unsigned short* __restrict__ W1l,
                                   unsigned short* __restrict__ W2h, unsigned short* __restrict__ W2l,
                                   unsigned short* __restrict__ uW1h, unsigned short* __restrict__ uW1l,
                                   unsigned short* __restrict__ uW2h, unsigned short* __restrict__ uW2l,
                                   unsigned short* __restrict__ UVh, unsigned short* __restrict__ UVl)
{
    int idx = blockIdx.x * blockDim.x + threadIdx.x;
    const float* src; unsigned short *th, *tl; int K, N, rem;
    if (idx < S0)                { src = msgW1; th = W1h;  tl = W1l;  K = 256; N = 256; rem = idx; }
    else if (idx < S0+S1)        { src = msgW2; th = W2h;  tl = W2l;  K = 256; N = 640; rem = idx - S0; }
    else if (idx < S0+S1+S2)     { src = updW1; th = uW1h; tl = uW1l; K = 256; N = 128; rem = idx - S0 - S1; }
    else if (idx < S0+S1+S2+S3)  { src = updW2; th = uW2h; tl = uW2l; K = 128; N = 384; rem = idx - S0 - S1 - S2; }
    else if (idx < S0+S1+S2+S3+S4) {
        // UVcat: [3][128][256] logical src, transposed out [3][256][128]
        rem = idx - S0 - S1 - S2 - S3;
        int ly = rem / (128 * 256);
        int r2 = rem % (128 * 256);
        int k = r2 >> 8, j = r2 & 255;
        float v = (j < 128) ? updU[(ly * 128 + k) * 128 + j]
                            : updV[(ly * 128 + k) * 128 + (j - 128)];
        unsigned short hh = f2bf_rne(v);
        size_t o = (size_t)ly * 128 * 256 + (size_t)j * 128 + k;
        UVh[o] = hh;
        UVl[o] = f2bf_rne(v - bf2f(hh));
        return;
    } else return;
    int l = rem / (K * N);
    int r2 = rem - l * (K * N);
    int k = r2 / N, n = r2 - k * N;
    float v = src[rem];
    unsigned short hh = f2bf_rne(v);
    size_t o = (size_t)l * K * N + (size_t)n * K + k;
    th[o] = hh;
    tl[o] = f2bf_rne(v - bf2f(hh));
}
#define WPREP_TOT (S0+S1+S2+S3+S4)

// ---------------------------------------------------------------------------
// Split-bf16 MFMA GEMM v5 (R10, PROTECTED): B pre-split + pre-transposed
// [N][K] staged through LDS; A through LDS. tile 64x64, BK=32, 4 waves.
// ---------------------------------------------------------------------------
template <int ACT, int CAT, int ASPLIT, int OSPLIT>
__global__ __launch_bounds__(256) void gemm5_kernel(
    const float* __restrict__ Af, const float* __restrict__ A1,
    const unsigned short* __restrict__ Agh, const unsigned short* __restrict__ Agl,
    const unsigned short* __restrict__ Wth, const unsigned short* __restrict__ Wtl,
    const float* __restrict__ bias,
    float* __restrict__ C, unsigned short* __restrict__ Ch, unsigned short* __restrict__ Cl,
    int M, int K, int N)
{
    __shared__ __align__(16) unsigned short Ah[64 * LDP];
    __shared__ __align__(16) unsigned short Al[64 * LDP];
    __shared__ __align__(16) unsigned short Bh[64 * LDP];
    __shared__ __align__(16) unsigned short Bl[64 * LDP];

    int tid = threadIdx.x;
    int row0 = blockIdx.y * 64, col0 = blockIdx.x * 64;
    int lane = tid & 63, wave = tid >> 6;
    int mb = (wave & 1) * 32, nb = (wave >> 1) * 32;
    int lm = lane & 15, quad = lane >> 4;

    f32x4 acc[2][2] = {};

    int sm = tid >> 2;           // 0..63: A row / B out-col
    int sk = (tid & 3) * 8;      // 0,8,16,24: k offset (8 elems)

    for (int k0 = 0; k0 < K; k0 += 32) {
        // ---- stage A: 64 rows x 32 k ----
        {
            int ar = row0 + sm;
            if (ASPLIT) {
                uint4 h = {0, 0, 0, 0}, l = {0, 0, 0, 0};
                if (ar < M) {
                    h = *(const uint4*)(Agh + (size_t)ar * K + k0 + sk);
                    l = *(const uint4*)(Agl + (size_t)ar * K + k0 + sk);
                }
                *(uint4*)&Ah[sm * LDP + sk] = h;
                *(uint4*)&Al[sm * LDP + sk] = l;
            } else {
                float4 a0 = make_float4(0.f, 0.f, 0.f, 0.f);
                float4 a1 = make_float4(0.f, 0.f, 0.f, 0.f);
                if (ar < M) {
                    int kk = k0 + sk;
                    const float* Ab;
                    if (CAT) Ab = (kk < 128) ? Af + (size_t)ar * 128 + kk
                                             : A1 + (size_t)ar * 128 + (kk - 128);
                    else     Ab = Af + (size_t)ar * K + kk;
                    a0 = *(const float4*)Ab;
                    a1 = *(const float4*)(Ab + 4);
                }
                float v[8] = {a0.x, a0.y, a0.z, a0.w, a1.x, a1.y, a1.z, a1.w};
                unsigned short hs[8], ls[8];
#pragma unroll
                for (int i = 0; i < 8; i++) {
                    unsigned short h = f2bf_rne(v[i]);
                    hs[i] = h; ls[i] = f2bf_rne(v[i] - bf2f(h));
                }
                *(uint4*)&Ah[sm * LDP + sk] = *(uint4*)hs;
                *(uint4*)&Al[sm * LDP + sk] = *(uint4*)ls;
            }
        }
        // ---- stage B: 64 out-cols x 32 k (already [n][k]) ----
        {
            size_t o = (size_t)(col0 + sm) * K + k0 + sk;
            uint4 h = *(const uint4*)(Wth + o);
            uint4 l = *(const uint4*)(Wtl + o);
            *(uint4*)&Bh[sm * LDP + sk] = h;
            *(uint4*)&Bl[sm * LDP + sk] = l;
        }
        __syncthreads();
        bf16x8 fah[2], fal[2], fbh[2], fbl[2];
#pragma unroll
        for (int mt = 0; mt < 2; mt++) {
            int r = mb + mt * 16 + lm;
            fah[mt] = *(const bf16x8*)&Ah[r * LDP + quad * 8];
            fal[mt] = *(const bf16x8*)&Al[r * LDP + quad * 8];
        }
#pragma unroll
        for (int nt = 0; nt < 2; nt++) {
            int n = nb + nt * 16 + lm;
            fbh[nt] = *(const bf16x8*)&Bh[n * LDP + quad * 8];
            fbl[nt] = *(const bf16x8*)&Bl[n * LDP + quad * 8];
        }
#pragma unroll
        for (int mt = 0; mt < 2; mt++)
#pragma unroll
            for (int nt = 0; nt < 2; nt++) {
                acc[mt][nt] = __builtin_amdgcn_mfma_f32_16x16x32_bf16(
                    fah[mt], fbh[nt], acc[mt][nt], 0, 0, 0);
                acc[mt][nt] = __builtin_amdgcn_mfma_f32_16x16x32_bf16(
                    fah[mt], fbl[nt], acc[mt][nt], 0, 0, 0);
                acc[mt][nt] = __builtin_amdgcn_mfma_f32_16x16x32_bf16(
                    fal[mt], fbh[nt], acc[mt][nt], 0, 0, 0);
            }
        __syncthreads();
    }
#pragma unroll
    for (int mt = 0; mt < 2; mt++)
#pragma unroll
        for (int nt = 0; nt < 2; nt++) {
            int c = col0 + nb + nt * 16 + lm;
            float bv = bias ? bias[c] : 0.f;
#pragma unroll
            for (int reg = 0; reg < 4; reg++) {
                int r = row0 + mb + mt * 16 + quad * 4 + reg;
                if (r >= M) continue;
                float v = acc[mt][nt][reg] + bv;
                if (ACT) v = v / (1.0f + expf(-v));
                if (OSPLIT) {
                    unsigned short h = f2bf_rne(v);
                    Ch[(size_t)r * N + c] = h;
                    Cl[(size_t)r * N + c] = f2bf_rne(v - bf2f(h));
                } else {
                    C[(size_t)r * N + c] = v;
                }
            }
        }
}

// ---------------------------------------------------------------------------
// Gather (R9, PROTECTED — byte-identical): plane-split halves, packed w-dot,
// distW pinned via opaque asm. L0=1 skips zero V/Vbar.
// ---------------------------------------------------------------------------
template <int L0>
__global__ __launch_bounds__(256, 4) void gather_kernel(
    const int* __restrict__ offsets, const int* __restrict__ dstP,
    const float4* __restrict__ ueP, const float* __restrict__ rbfP,
    const float* __restrict__ phi,
    const float* __restrict__ distW, const float* __restrict__ distb,
    const float* __restrict__ Vold, const float* __restrict__ Vbold,
    float* __restrict__ H, float* __restrict__ Sbar,
    float* __restrict__ Vnew, float* __restrict__ Vbnew)
{
    int n = blockIdx.x;
    int t = threadIdx.x;
    int half = t >> 7;          // wave-uniform
    int f = t & 127;
    int po = half * 256;

    v2f wv2[30];
#pragma unroll
    for (int q = 0; q < 10; q++)
#pragma unroll
        for (int c = 0; c < 3; c++) {
            wv2[q * 3 + c].x = distW[(2 * q) * 640 + po + c * 128 + f];
            wv2[q * 3 + c].y = distW[(2 * q + 1) * 640 + po + c * 128 + f];
        }
#pragma unroll
    for (int i = 0; i < 30; i++) asm volatile("" : "+v"(wv2[i]));

    float bA = distb[po + f], bB = distb[po + 128 + f], bC = distb[po + 256 + f];

    const float* Vsel = half ? Vbold : Vold;

    float sacc = 0.f, acc0 = 0.f, acc1 = 0.f, acc2 = 0.f;
    int e0 = offsets[n], e1 = offsets[n + 1];
    for (int p = e0; p < e1; ++p) {
        int d = dstP[p];
        float4 ue = ueP[p];
        float r[NRBF];
#pragma unroll
        for (int q = 0; q < NRBF / 4; q++) {
            float4 rv = *(const float4*)&rbfP[NRBF * p + 4 * q];
            r[4 * q + 0] = rv.x; r[4 * q + 1] = rv.y;
            r[4 * q + 2] = rv.z; r[4 * q + 3] = rv.w;
        }
        v2f aA = {0.f, 0.f}, aB = {0.f, 0.f}, aC = {0.f, 0.f};
#pragma unroll
        for (int q = 0; q < 10; q++) {
            v2f r2; r2.x = r[2 * q]; r2.y = r[2 * q + 1];
            aA += r2 * wv2[q * 3 + 0];
            aB += r2 * wv2[q * 3 + 1];
            aC += r2 * wv2[q * 3 + 2];
        }
        float ev = ue.w;
        float wA = (aA.x + aA.y + bA) * ev;
        float wB = (aB.x + aB.y + bB) * ev;
        float wC = (aC.x + aC.y + bC) * ev;
        const float* ph = phi + (size_t)d * 640 + po;
        float iA = ph[f] * wA;
        float iB = ph[128 + f] * wB;
        float iC = ph[256 + f] * wC;
        float dir = half ? iA : iC;
        sacc += iB;
        if (L0) {
            acc0 += dir * ue.x;
            acc1 += dir * ue.y;
            acc2 += dir * ue.z;
        } else {
            float gate = half ? iC : iA;
            const float* vd = Vsel + (size_t)d * 384;
            acc0 += dir * ue.x + gate * vd[f];
            acc1 += dir * ue.y + gate * vd[128 + f];
            acc2 += dir * ue.z + gate * vd[256 + f];
        }
    }
    if (half == 0) H[n * 128 + f] += sacc;
    else           Sbar[n * 128 + f] += sacc;
    float* vn = (half ? Vbnew : Vnew) + (size_t)n * 384;
    if (L0) {
        vn[f] = acc0; vn[128 + f] = acc1; vn[256 + f] = acc2;
    } else {
        const float* vo = Vsel + (size_t)n * 384;
        vn[f]       = vo[f]       + acc0;
        vn[128 + f] = vo[128 + f] + acc1;
        vn[256 + f] = vo[256 + f] + acc2;
    }
}

// ---------------------------------------------------------------------------
// norm/dot from fused uv2 [3N x 256].
// ---------------------------------------------------------------------------
__global__ void norm_kernel(const float* __restrict__ uv2,
                            float* __restrict__ vnorm, float* __restrict__ dotb)
{
    int idx = blockIdx.x * blockDim.x + threadIdx.x;
    if (idx >= NN * 128) return;
    int n = idx >> 7, g = idx & 127;
    const float* base = uv2 + (size_t)n * 768;
    float u0 = base[g],       u1 = base[256 + g], u2 = base[512 + g];
    float v0 = base[128 + g], v1 = base[384 + g], v2 = base[640 + g];
    dotb[idx] = u0 * v0 + u1 * v1 + u2 * v2;
    vnorm[idx] = sqrtf(v0 * v0 + v1 * v1 + v2 * v2 + 1e-15f);
}

// ---------------------------------------------------------------------------
// Final per-layer update: H += a1*dot + a2 ; V += a0*u_v (u from uv2).
// ---------------------------------------------------------------------------
template <int LAST>
__global__ void final_update_kernel(const float* __restrict__ a,
                                    const float* __restrict__ dotb,
                                    const float* __restrict__ uv2,
                                    float* __restrict__ H,
                                    float* __restrict__ Vplanar,
                                    float* __restrict__ Vout)
{
    int idx = blockIdx.x * blockDim.x + threadIdx.x;
    if (idx >= NN * 128) return;
    int n = idx >> 7, g = idx & 127;
    float a0 = a[n * 384 + g];
    float a1 = a[n * 384 + 128 + g];
    float a2 = a[n * 384 + 256 + g];
    H[idx] += a1 * dotb[idx] + a2;
    float* vp = Vplanar + (size_t)n * 384;
    const float* ub = uv2 + (size_t)n * 768;
    float v0 = vp[g]       + a0 * ub[g];
    float v1 = vp[128 + g] + a0 * ub[256 + g];
    float v2 = vp[256 + g] + a0 * ub[512 + g];
    if (LAST) {
        float* o = Vout + (size_t)n * 384 + g * 3;
        o[0] = v0; o[1] = v1; o[2] = v2;
    } else {
        vp[g] = v0; vp[128 + g] = v1; vp[256 + g] = v2;
    }
}

// ---------------------------------------------------------------------------
extern "C" void kernel_launch(void* const* d_in, const int* in_sizes, int n_in,
                              void* d_out, int out_size, void* d_ws, size_t ws_size,
                              hipStream_t stream)
{
    const float* xyz    = (const float*)d_in[0];
    const int*   nbr    = (const int*)d_in[1];
    const float* H_in   = (const float*)d_in[3];
    const float* msgW1  = (const float*)d_in[4];
    const float* msgb1  = (const float*)d_in[5];
    const float* msgW2  = (const float*)d_in[6];
    const float* msgb2  = (const float*)d_in[7];
    const float* distW  = (const float*)d_in[8];
    const float* distb  = (const float*)d_in[9];
    const float* updU   = (const float*)d_in[10];
    const float* updV   = (const float*)d_in[11];
    const float* updW1  = (const float*)d_in[12];
    const float* updb1  = (const float*)d_in[13];
    const float* updW2  = (const float*)d_in[14];
    const float* updb2  = (const float*)d_in[15];

    float* out  = (float*)d_out;
    float* H    = out;                 // N*128
    float* Vout = out + NN * 128;      // N*384 interleaved (n,f,3)

    // ---- workspace carve ----
    float* f = (float*)d_ws;
    float* Va   = f; f += NN * 384;    // planar V buffers
    float* Vb   = f; f += NN * 384;
    float* Vba  = f; f += NN * 384;
    float* Vbb  = f; f += NN * 384;
    float* Sbar = f; f += NN * 128;
    float* phi  = f; f += NN * 640;
    float* uv2  = f; f += NN * 768;    // [3N x 256] fused u_v|v_v
    float4* ueP = (float4*)f; f += NE * 4;
    float* rbfP  = f; f += NE * NRBF;
    unsigned short* us = (unsigned short*)f;
    unsigned short* X1h = us; us += NN * 256;
    unsigned short* X1l = us; us += NN * 256;
    unsigned short* W1h = us; us += 3 * 256 * 256;   // transposed [N=256][K=256]
    unsigned short* W1l = us; us += 3 * 256 * 256;
    unsigned short* W2h = us; us += 3 * 256 * 640;   // transposed [N=640][K=256]
    unsigned short* W2l = us; us += 3 * 256 * 640;
    unsigned short* UVh = us; us += 3 * 128 * 256;   // transposed [N=256][K=128]
    unsigned short* UVl = us; us += 3 * 128 * 256;
    unsigned short* uW1h = us; us += 3 * 256 * 128;  // transposed [N=128][K=256]
    unsigned short* uW1l = us; us += 3 * 256 * 128;
    unsigned short* uW2h = us; us += 3 * 128 * 384;  // transposed [N=384][K=128]
    unsigned short* uW2l = us; us += 3 * 128 * 384;
    int* ip = (int*)(((size_t)us + 15) & ~(size_t)15);
    int* counts  = ip; ip += NN;
    int* offsets = ip; ip += NN + 1;
    int* cnt2    = ip; ip += NN;
    int* dstP    = ip; ip += NE;
    // aliases into dead phi region (phi dead after gather each layer)
    float* vnorm = phi;
    float* dotb  = phi + NN * 128;
    float* abuf  = phi + NN * 256;     // N*384

    // ---- init ----
    hipMemsetAsync(counts, 0, NN * sizeof(int), stream);
    hipMemsetAsync(cnt2, 0, NN * sizeof(int), stream);
    hipMemsetAsync(Sbar, 0, (size_t)NN * 128 * sizeof(float), stream);
    hipMemcpyAsync(H, H_in, (size_t)NN * 128 * sizeof(float),
                   hipMemcpyDeviceToDevice, stream);

    // ---- edge CSR + geometry + merged weight prep ----
    edge_count_kernel<<<(NE + 255) / 256, 256, 0, stream>>>(nbr, counts);
    scan_kernel<<<1, 1024, 0, stream>>>(counts, offsets);
    edge_geom_fill_kernel<<<(NE + 255) / 256, 256, 0, stream>>>(xyz, nbr, offsets, cnt2,
                                                                dstP, ueP, rbfP);
    weight_prep_kernel<<<(WPREP_TOT + 255) / 256, 256, 0, stream>>>(
        msgW1, msgW2, updW1, updW2, updU, updV,
        W1h, W1l, W2h, W2l, uW1h, uW1l, uW2h, uW2l, UVh, UVl);

    for (int l = 0; l < 3; ++l) {
        const float* b1 = msgb1 + (size_t)l * 256;
        const float* b2 = msgb2 + (size_t)l * 640;
        const float* dW = distW + (size_t)l * NRBF * 640;
        const float* db = distb + (size_t)l * 640;
        const float* ub1 = updb1 + (size_t)l * 128;
        const float* ub2 = updb2 + (size_t)l * 384;
        const unsigned short *w1h = W1h + (size_t)l * 256 * 256, *w1l = W1l + (size_t)l * 256 * 256;
        const unsigned short *w2h = W2h + (size_t)l * 256 * 640, *w2l = W2l + (size_t)l * 256 * 640;
        const unsigned short *uvh = UVh + (size_t)l * 128 * 256, *uvl = UVl + (size_t)l * 128 * 256;
        const unsigned short *u1h = uW1h + (size_t)l * 256 * 128, *u1l = uW1l + (size_t)l * 256 * 128;
        const unsigned short *u2h = uW2h + (size_t)l * 128 * 384, *u2l = uW2l + (size_t)l * 128 * 384;

        float *Vold, *Vnew, *Vbold, *Vbnew;
        if (l == 0)      { Vold = Va; Vnew = Vb; Vbold = Vba; Vbnew = Vbb; }
        else if (l == 1) { Vold = Vb; Vnew = Va; Vbold = Vbb; Vbnew = Vba; }
        else             { Vold = Va; Vnew = Vb; Vbold = Vba; Vbnew = Vbb; }

        // X1 = silu([H|Sbar] @ W1 + b1)  (split-bf16 output)
        {
            dim3 g(256 / 64, (NN + 63) / 64);
            gemm5_kernel<1, 1, 0, 1><<<g, 256, 0, stream>>>(
                H, Sbar, nullptr, nullptr, w1h, w1l, b1,
                nullptr, X1h, X1l, NN, 256, 256);
        }
        // phi = X1 @ W2 + b2  (fp32 output)
        {
            dim3 g(640 / 64, (NN + 63) / 64);
            gemm5_kernel<0, 0, 1, 0><<<g, 256, 0, stream>>>(
                nullptr, nullptr, X1h, X1l, w2h, w2l, b2,
                phi, nullptr, nullptr, NN, 256, 640);
        }

        // message gather
        if (l == 0)
            gather_kernel<1><<<NN, 256, 0, stream>>>(offsets, dstP, ueP, rbfP,
                                                     phi, dW, db, Vold, Vbold,
                                                     H, Sbar, Vnew, Vbnew);
        else
            gather_kernel<0><<<NN, 256, 0, stream>>>(offsets, dstP, ueP, rbfP,
                                                     phi, dW, db, Vold, Vbold,
                                                     H, Sbar, Vnew, Vbnew);

        // uv2[3N x 256] = Vplanar[3N x 128] @ [U|V]
        {
            dim3 g(256 / 64, (3 * NN + 63) / 64);
            gemm5_kernel<0, 0, 0, 0><<<g, 256, 0, stream>>>(
                Vnew, nullptr, nullptr, nullptr, uvh, uvl, nullptr,
                uv2, nullptr, nullptr, 3 * NN, 128, 256);
        }
        norm_kernel<<<(NN * 128 + 255) / 256, 256, 0, stream>>>(uv2, vnorm, dotb);

        // X1 = silu([H|vnorm] @ uW1 + ub1)  (split output, 128 wide)
        {
            dim3 g(128 / 64, (NN + 63) / 64);
            gemm5_kernel<1, 1, 0, 1><<<g, 256, 0, stream>>>(
                H, vnorm, nullptr, nullptr, u1h, u1l, ub1,
                nullptr, X1h, X1l, NN, 256, 128);
        }
        // abuf = X1 @ uW2 + ub2
        {
            dim3 g(384 / 64, (NN + 63) / 64);
            gemm5_kernel<0, 0, 1, 0><<<g, 256, 0, stream>>>(
                nullptr, nullptr, X1h, X1l, u2h, u2l, ub2,
                abuf, nullptr, nullptr, NN, 128, 384);
        }

        // H += a1*dot + a2 ; V += a0*u_v
        if (l < 2)
            final_update_kernel<0><<<(NN * 128 + 255) / 256, 256, 0, stream>>>(
                abuf, dotb, uv2, H, Vnew, nullptr);
        else
            final_update_kernel<1><<<(NN * 128 + 255) / 256, 256, 0, stream>>>(
                abuf, dotb, uv2, H, Vnew, Vout);
    }
}